// Round 6
// baseline (184.074 us; speedup 1.0000x reference)
//
#include <hip/hip_runtime.h>
#include <hip/hip_bf16.h>
#include <stdint.h>

// Problem constants (from reference)
#define B_   32
#define C_   3
#define H_   384
#define W_   384
#define HW_  (H_ * W_)      // 147456
#define N_   576
#define ED   768            // embed dim (output features)
#define KF   768            // in features = 3*16*16
#define M_   (B_ * N_)      // 18432 patch rows
#define NT   (KF / 64)      // 12 K-iters

typedef __attribute__((ext_vector_type(8))) short   short8;
typedef __attribute__((ext_vector_type(8))) unsigned short ushort8;
typedef __attribute__((ext_vector_type(4))) float   f32x4;
typedef __attribute__((ext_vector_type(4))) unsigned int uint4v;

// fp32 -> bf16 with round-to-nearest-even (used for W only)
__device__ __forceinline__ unsigned short f2bf(float f) {
    union { float f; unsigned int u; } v; v.f = f;
    unsigned int u = v.u;
    return (unsigned short)((u + 0x7FFFu + ((u >> 16) & 1u)) >> 16);
}

// ---------------------------------------------------------------------------
// Kernel 1: proj_w fp32 -> bf16 [ED][KF] row-major (B^T layout, K contiguous)
// ---------------------------------------------------------------------------
__global__ __launch_bounds__(256) void conv_w(
    const float* __restrict__ w, unsigned short* __restrict__ Wb) {
    int gid = blockIdx.x * 256 + threadIdx.x;          // ED*KF/8 threads
    const float4* s = (const float4*)w + (size_t)gid * 2;
    float4 a = s[0], bq = s[1];
    ushort8 o;
    o[0] = f2bf(a.x);  o[1] = f2bf(a.y);  o[2] = f2bf(a.z);  o[3] = f2bf(a.w);
    o[4] = f2bf(bq.x); o[5] = f2bf(bq.y); o[6] = f2bf(bq.z); o[7] = f2bf(bq.w);
    *(ushort8*)(Wb + (size_t)gid * 8) = o;
}

// ---------------------------------------------------------------------------
// Kernel 2: FUSED gather + bf16 GEMM with T14 register prefetch.
// Same 2-barrier schedule as round 4/5. Change vs round 5: the 32 A-gather
// dword loads for iter kt+1 are ISSUED right after barrier1 of iter kt
// (inside the ds_read+MFMA phase); the forced vmcnt(0) at barrier2 drains
// them under ~260cy of compute cover, so the pack at kt+1 reads ready regs
// instead of waiting on fresh loads (round-5's 12x serial latency exposure).
// ---------------------------------------------------------------------------
#define GLD16(g, l)                                                        \
    __builtin_amdgcn_global_load_lds(                                      \
        (const __attribute__((address_space(1))) unsigned int*)(g),        \
        (__attribute__((address_space(3))) unsigned int*)(l), 16, 0, 0)

#define BK 64

__device__ __forceinline__ unsigned int pkbf(unsigned int hi, unsigned int lo) {
    // word = bf16(lo) | bf16(hi)<<16 (inputs pre-biased for round-half-up)
    return __builtin_amdgcn_perm(hi, lo, 0x07060302);
}

__device__ __forceinline__ void load_rows(const float* __restrict__ xb, int kt,
                                          int p0, unsigned int* ua,
                                          unsigned int* ub) {
    const int c   = kt >> 2;
    const int ph0 = (kt & 3) * 4;
    const float* r0p = xb + (size_t)c * HW_ + (size_t)(ph0 + p0) * W_;
    const float* r1p = r0p + 2 * W_;
#pragma unroll
    for (int i = 0; i < 16; ++i) {
        union { float f; unsigned int u; } cv;
        cv.f = r0p[i]; ua[i] = cv.u;
        cv.f = r1p[i]; ub[i] = cv.u;
    }
}

__global__ __launch_bounds__(256) void gemm_fused(
    const float* __restrict__ x, const int* __restrict__ h_idx,
    const int* __restrict__ w_idx, const unsigned short* __restrict__ Wb,
    const float* __restrict__ bias, float* __restrict__ out) {
    __shared__ unsigned short sA[128 * BK];   // 16 KiB
    __shared__ unsigned short sB[128 * BK];   // 16 KiB

    const int t = threadIdx.x;

    // XCD-aware bijective block swizzle (864 % 8 == 0)
    const int lin = blockIdx.y * 6 + blockIdx.x;
    const int swz = (lin & 7) * 108 + (lin >> 3);
    const int m0  = (swz / 6) * 128;
    const int e0  = (swz % 6) * 128;

    const int lane = t & 63;
    const int wid  = t >> 6;
    const int wr   = wid >> 1;
    const int wc   = wid & 1;
    const int r16  = lane & 15;
    const int kh   = lane >> 4;

    // ---- A-gather per-thread invariants ----
    const int m_loc = t & 127;
    const int p0    = t >> 7;               // 0 or 1; second row is p0+2
    const int m     = m0 + m_loc;
    const int bb    = m / N_;
    const int h     = h_idx[m];
    const int w     = w_idx[m];
    const float* xb = x + (size_t)(bb * C_) * HW_ + (size_t)h * W_ + w;
    const int m7 = m_loc & 7;
    char* sAb = (char*)sA;
    const int rb  = m_loc * 128;            // row byte base (64 bf16 = 128B)
    const int a00 = rb + (((2 * p0    ) ^ m7) << 4);
    const int a01 = rb + (((2 * p0 + 1) ^ m7) << 4);
    const int a10 = rb + (((2 * p0 + 4) ^ m7) << 4);   // p0+2 -> slots 2p0+4/5
    const int a11 = rb + (((2 * p0 + 5) ^ m7) << 4);

    // ---- B staging source precompute (source-side slot swizzle) ----
    int st_row[4], st_gc[4];
#pragma unroll
    for (int r = 0; r < 4; ++r) {
        const int o   = r * 4096 + t * 16;
        const int row = o >> 7;
        const int s   = (o >> 4) & 7;
        st_row[r] = row;
        st_gc[r]  = (s ^ (row & 7)) * 8;
    }

    f32x4 acc[4][4];
#pragma unroll
    for (int i = 0; i < 4; ++i)
#pragma unroll
        for (int j = 0; j < 4; ++j) acc[i][j] = (f32x4)0.0f;

    unsigned int ua[16], ub[16];
    load_rows(xb, 0, p0, ua, ub);           // prologue: iter-0 gather

    for (int kt = 0; kt < NT; ++kt) {
        const int k0 = kt * BK;

        // B-tile staging (16 KiB, 4 x GLD16 per thread)
#pragma unroll
        for (int r = 0; r < 4; ++r)
            GLD16(Wb + (size_t)(e0 + st_row[r]) * KF + k0 + st_gc[r],
                  (char*)sB + r * 4096 + t * 16);

        // Pack prefetched regs (iter kt) -> bf16 -> swizzled LDS
        {
            unsigned int q[16];
#pragma unroll
            for (int i = 0; i < 16; ++i) q[i] = ua[i] + 0x8000u;
            uint4v lo = { pkbf(q[1], q[0]),   pkbf(q[3], q[2]),
                          pkbf(q[5], q[4]),   pkbf(q[7], q[6]) };
            uint4v hi = { pkbf(q[9], q[8]),   pkbf(q[11], q[10]),
                          pkbf(q[13], q[12]), pkbf(q[15], q[14]) };
            *(uint4v*)(sAb + a00) = lo;
            *(uint4v*)(sAb + a01) = hi;
#pragma unroll
            for (int i = 0; i < 16; ++i) q[i] = ub[i] + 0x8000u;
            uint4v lo2 = { pkbf(q[1], q[0]),   pkbf(q[3], q[2]),
                           pkbf(q[5], q[4]),   pkbf(q[7], q[6]) };
            uint4v hi2 = { pkbf(q[9], q[8]),   pkbf(q[11], q[10]),
                           pkbf(q[13], q[12]), pkbf(q[15], q[14]) };
            *(uint4v*)(sAb + a10) = lo2;
            *(uint4v*)(sAb + a11) = hi2;
        }
        __syncthreads();   // barrier1: drains B GLD16 + A ds_writes

        // T14: issue NEXT iter's gather loads now — they drain at barrier2
        // under the ds_read+MFMA cover below.
        if (kt + 1 < NT) load_rows(xb, kt + 1, p0, ua, ub);

#pragma unroll
        for (int kk = 0; kk < 2; ++kk) {
            short8 af[4], bf[4];
#pragma unroll
            for (int mi = 0; mi < 4; ++mi) {
                const int ar = wr * 64 + mi * 16 + r16;
                const int sl = ((kk << 2) + kh) ^ (ar & 7);
                af[mi] = *(const short8*)&sA[ar * BK + sl * 8];
            }
#pragma unroll
            for (int ni = 0; ni < 4; ++ni) {
                const int br = wc * 64 + ni * 16 + r16;
                const int sl = ((kk << 2) + kh) ^ (br & 7);
                bf[ni] = *(const short8*)&sB[br * BK + sl * 8];
            }
#pragma unroll
            for (int mi = 0; mi < 4; ++mi)
#pragma unroll
                for (int ni = 0; ni < 4; ++ni)
                    acc[mi][ni] = __builtin_amdgcn_mfma_f32_16x16x32_bf16(
                        af[mi], bf[ni], acc[mi][ni], 0, 0, 0);
        }
        __syncthreads();   // barrier2: drains prefetch loads (overlapped)
    }

    // Epilogue: C/D layout col = lane&15, row = (lane>>4)*4 + j  [m89]
#pragma unroll
    for (int mi = 0; mi < 4; ++mi) {
#pragma unroll
        for (int ni = 0; ni < 4; ++ni) {
            const int ge = e0 + wc * 64 + ni * 16 + r16;
            const float bv = bias[ge];
#pragma unroll
            for (int j = 0; j < 4; ++j) {
                const int gm = m0 + wr * 64 + mi * 16 + kh * 4 + j;
                out[(size_t)gm * ED + ge] = acc[mi][ni][j] + bv;
            }
        }
    }
}

// ---------------------------------------------------------------------------
extern "C" void kernel_launch(void* const* d_in, const int* in_sizes, int n_in,
                              void* d_out, int out_size, void* d_ws, size_t ws_size,
                              hipStream_t stream) {
    const float* x      = (const float*)d_in[0];
    const int*   h_idx  = (const int*)  d_in[1];
    const int*   w_idx  = (const int*)  d_in[2];
    const float* proj_w = (const float*)d_in[3];
    const float* proj_b = (const float*)d_in[4];
    float*       out    = (float*)d_out;

    // Workspace: only Wb bf16 [ED][KF] (1.2 MB) — A is gathered in-GEMM.
    unsigned short* Wws = (unsigned short*)d_ws;

    conv_w<<<(ED * KF / 8) / 256, 256, 0, stream>>>(proj_w, Wws);
    gemm_fused<<<dim3(ED / 128, M_ / 128), 256, 0, stream>>>(
        x, h_idx, w_idx, Wws, proj_b, out);
}

// Round 7
// 158.341 us; speedup vs baseline: 1.1625x; 1.1625x over previous
//
#include <hip/hip_runtime.h>
#include <hip/hip_bf16.h>
#include <stdint.h>

// Problem constants (from reference)
#define B_   32
#define C_   3
#define H_   384
#define W_   384
#define HW_  (H_ * W_)      // 147456
#define N_   576
#define ED   768            // embed dim (output features)
#define KF   768            // in features = 3*16*16
#define M_   (B_ * N_)      // 18432 patch rows

typedef __attribute__((ext_vector_type(8))) short   short8;
typedef __attribute__((ext_vector_type(8))) unsigned short ushort8;
typedef __attribute__((ext_vector_type(4))) float   f32x4;
typedef __attribute__((ext_vector_type(4))) unsigned int uint4v;

// fp32 -> bf16 with round-to-nearest-even (used for W only)
__device__ __forceinline__ unsigned short f2bf(float f) {
    union { float f; unsigned int u; } v; v.f = f;
    unsigned int u = v.u;
    return (unsigned short)((u + 0x7FFFu + ((u >> 16) & 1u)) >> 16);
}

// bf16 pair pack: word = bf16(lo) | bf16(hi)<<16 (inputs pre-biased +0x8000
// for round-half-up; matches rounds 5/6 which measured identical absmax)
__device__ __forceinline__ unsigned int pkbf(unsigned int hi, unsigned int lo) {
    return __builtin_amdgcn_perm(hi, lo, 0x07060302);
}

// ---------------------------------------------------------------------------
// Kernel 1: gather patches -> bf16 A matrix [M_][KF], row-major.  v2:
// one thread = patch-rows (c,ph) and (c,ph+8): two 64B reads (8 dwordx4 in
// flight), +0x8000 bias + v_perm pack, 4x16B contiguous stores (8 lanes tile
// 512B per (m,c)). 442K threads (4x fewer than v1) -> index overhead /4.
// f = c*256 + ph*16 + pw (reference transpose (0,1,4,2,3) ordering).
// ---------------------------------------------------------------------------
__global__ __launch_bounds__(256) void gather_patches(
    const float* __restrict__ x, const int* __restrict__ h_idx,
    const int* __restrict__ w_idx, unsigned short* __restrict__ Aws) {
    const int gid = blockIdx.x * 256 + threadIdx.x;   // M_*24 threads total
    const int m   = gid / 24;                         // const-divide (magic)
    const int rr  = gid - m * 24;
    const int c   = rr >> 3;                          // 0..2
    const int ph  = rr & 7;                           // row pair: ph, ph+8
    const int b   = m / N_;
    const int h   = h_idx[m] + ph;
    const int w   = w_idx[m];
    const float* src0 = x + ((size_t)(b * C_ + c)) * HW_ + (size_t)h * W_ + w;
    const float* src1 = src0 + 8 * W_;                // row ph+8

    float f0[16], f1[16];
    __builtin_memcpy(f0, src0, 64);                   // 4B-aligned 64B
    __builtin_memcpy(f1, src1, 64);

    unsigned int u0[16], u1[16];
#pragma unroll
    for (int i = 0; i < 16; ++i) {
        union { float f; unsigned int u; } cv;
        cv.f = f0[i]; u0[i] = cv.u + 0x8000u;
        cv.f = f1[i]; u1[i] = cv.u + 0x8000u;
    }
    uint4v a0 = { pkbf(u0[1], u0[0]),   pkbf(u0[3], u0[2]),
                  pkbf(u0[5], u0[4]),   pkbf(u0[7], u0[6]) };
    uint4v a1 = { pkbf(u0[9], u0[8]),   pkbf(u0[11], u0[10]),
                  pkbf(u0[13], u0[12]), pkbf(u0[15], u0[14]) };
    uint4v b0 = { pkbf(u1[1], u1[0]),   pkbf(u1[3], u1[2]),
                  pkbf(u1[5], u1[4]),   pkbf(u1[7], u1[6]) };
    uint4v b1 = { pkbf(u1[9], u1[8]),   pkbf(u1[11], u1[10]),
                  pkbf(u1[13], u1[12]), pkbf(u1[15], u1[14]) };

    unsigned short* dst = Aws + (size_t)m * KF + c * 256 + ph * 16;
    *(uint4v*)(dst)       = a0;          // row ph,   pw 0..7
    *(uint4v*)(dst + 8)   = a1;          // row ph,   pw 8..15
    *(uint4v*)(dst + 128) = b0;          // row ph+8, pw 0..7
    *(uint4v*)(dst + 136) = b1;          // row ph+8, pw 8..15
}

// ---------------------------------------------------------------------------
// Kernel 2: proj_w fp32 -> bf16 [ED][KF] row-major (B^T layout, K contiguous)
// ---------------------------------------------------------------------------
__global__ __launch_bounds__(256) void conv_w(
    const float* __restrict__ w, unsigned short* __restrict__ Wb) {
    int gid = blockIdx.x * 256 + threadIdx.x;          // ED*KF/8 threads
    const float4* s = (const float4*)w + (size_t)gid * 2;
    float4 a = s[0], bq = s[1];
    ushort8 o;
    o[0] = f2bf(a.x);  o[1] = f2bf(a.y);  o[2] = f2bf(a.z);  o[3] = f2bf(a.w);
    o[4] = f2bf(bq.x); o[5] = f2bf(bq.y); o[6] = f2bf(bq.z); o[7] = f2bf(bq.w);
    *(ushort8*)(Wb + (size_t)gid * 8) = o;
}

// ---------------------------------------------------------------------------
// Kernel 3: bf16 GEMM — byte-identical to round 4 (measured 41.7us,
// MfmaUtil 19.4%, SQ_LDS_BANK_CONFLICT = 0). 128x128 tile, BK=64,
// source-side T2 XOR swizzle + bijective XCD swizzle.
// ---------------------------------------------------------------------------
#define GLD16(g, l)                                                        \
    __builtin_amdgcn_global_load_lds(                                      \
        (const __attribute__((address_space(1))) unsigned int*)(g),        \
        (__attribute__((address_space(3))) unsigned int*)(l), 16, 0, 0)

#define BK 64

__global__ __launch_bounds__(256) void gemm_bt(
    const unsigned short* __restrict__ A, const unsigned short* __restrict__ Wb,
    const float* __restrict__ bias, float* __restrict__ out) {
    __shared__ unsigned short sA[128 * BK];   // 16 KiB
    __shared__ unsigned short sB[128 * BK];   // 16 KiB

    const int t = threadIdx.x;

    // XCD-aware block swizzle: dispatch-linear id -> (e_tile, m_tile)
    const int lin = blockIdx.y * 6 + blockIdx.x;     // x-fastest dispatch order
    const int swz = (lin & 7) * 108 + (lin >> 3);    // 864/8 = 108, bijective
    const int m0  = (swz / 6) * 128;
    const int e0  = (swz % 6) * 128;

    const int lane = t & 63;
    const int wid  = t >> 6;
    const int wr   = wid >> 1;       // wave row (0..1)
    const int wc   = wid & 1;        // wave col (0..1)
    const int r16  = lane & 15;
    const int kh   = lane >> 4;      // 0..3

    f32x4 acc[4][4];
#pragma unroll
    for (int i = 0; i < 4; ++i)
#pragma unroll
        for (int j = 0; j < 4; ++j) acc[i][j] = (f32x4)0.0f;

    // Staging addressing: round r, byte o = r*4096 + t*16; row = o>>7;
    // slot s = (o>>4)&7; source slot g = s ^ (row&7); source col = g*8.
    int st_row[4], st_gc[4];
#pragma unroll
    for (int r = 0; r < 4; ++r) {
        const int o   = r * 4096 + t * 16;
        const int row = o >> 7;
        const int s   = (o >> 4) & 7;
        st_row[r] = row;
        st_gc[r]  = (s ^ (row & 7)) * 8;
    }

    for (int kt = 0; kt < KF / BK; ++kt) {
        const int k0 = kt * BK;
#pragma unroll
        for (int r = 0; r < 4; ++r) {
            const int o = r * 4096 + t * 16;
            GLD16(A  + (size_t)(m0 + st_row[r]) * KF + k0 + st_gc[r], (char*)sA + o);
            GLD16(Wb + (size_t)(e0 + st_row[r]) * KF + k0 + st_gc[r], (char*)sB + o);
        }
        __syncthreads();

#pragma unroll
        for (int kk = 0; kk < 2; ++kk) {
            short8 af[4], bf[4];
#pragma unroll
            for (int mi = 0; mi < 4; ++mi) {
                const int ar = wr * 64 + mi * 16 + r16;
                const int sl = ((kk << 2) + kh) ^ (ar & 7);
                af[mi] = *(const short8*)&sA[ar * BK + sl * 8];
            }
#pragma unroll
            for (int ni = 0; ni < 4; ++ni) {
                const int br = wc * 64 + ni * 16 + r16;
                const int sl = ((kk << 2) + kh) ^ (br & 7);
                bf[ni] = *(const short8*)&sB[br * BK + sl * 8];
            }
#pragma unroll
            for (int mi = 0; mi < 4; ++mi)
#pragma unroll
                for (int ni = 0; ni < 4; ++ni)
                    acc[mi][ni] = __builtin_amdgcn_mfma_f32_16x16x32_bf16(
                        af[mi], bf[ni], acc[mi][ni], 0, 0, 0);
        }
        __syncthreads();
    }

    // Epilogue: C/D layout col = lane&15, row = (lane>>4)*4 + j  [m89]
#pragma unroll
    for (int mi = 0; mi < 4; ++mi) {
#pragma unroll
        for (int ni = 0; ni < 4; ++ni) {
            const int ge = e0 + wc * 64 + ni * 16 + r16;
            const float bv = bias[ge];
#pragma unroll
            for (int j = 0; j < 4; ++j) {
                const int gm = m0 + wr * 64 + mi * 16 + kh * 4 + j;
                out[(size_t)gm * ED + ge] = acc[mi][ni][j] + bv;
            }
        }
    }
}

// ---------------------------------------------------------------------------
extern "C" void kernel_launch(void* const* d_in, const int* in_sizes, int n_in,
                              void* d_out, int out_size, void* d_ws, size_t ws_size,
                              hipStream_t stream) {
    const float* x      = (const float*)d_in[0];
    const int*   h_idx  = (const int*)  d_in[1];
    const int*   w_idx  = (const int*)  d_in[2];
    const float* proj_w = (const float*)d_in[3];
    const float* proj_b = (const float*)d_in[4];
    float*       out    = (float*)d_out;

    // Workspace: A bf16 [M_][KF] (28.3 MB) then Wb bf16 [ED][KF] (1.2 MB).
    unsigned short* Aws = (unsigned short*)d_ws;
    unsigned short* Wws = Aws + (size_t)M_ * KF;

    gather_patches<<<M_ * 24 / 256, 256, 0, stream>>>(x, h_idx, w_idx, Aws);
    conv_w<<<(ED * KF / 8) / 256, 256, 0, stream>>>(proj_w, Wws);
    gemm_bt<<<dim3(ED / 128, M_ / 128), 256, 0, stream>>>(Aws, Wws, proj_b, out);
}